// Round 1
// baseline (4066.318 us; speedup 1.0000x reference)
//
#include <hip/hip_runtime.h>
#include <math.h>

#define NTAU 82
#define TMIN 28
#define S_TOT 5617
#define TF 6000
#define BATCH 4
#define WMAX 28
#define AP 84          // A row pitch: 82 + 2 pad cols (invalid-slot emit target)
#define NSLOT 6
#define NTHREADS 1024

// ws layout (float offsets)
#define TRANS_OFF 0            // 82*82 floats
#define BLP_OFF   8192         // 4*6000
#define NBLP_OFF  32768        // 4*6000
#define AH_OFF    57344        // 4*6000*84  (A history for backtrace argmax recompute)
// total = 57344 + 2016000 floats = ~8.3 MB

__device__ __forceinline__ int first_of(int b) { return b * (55 + b) / 2; }

__device__ __forceinline__ float logsig(float x) {
    // jax log_sigmoid(x) = -logaddexp(-x, 0) = -(max(-x,0) + log1p(exp(-|x|)))
    return -(fmaxf(-x, 0.0f) + log1pf(expf(-fabsf(x))));
}

// ---------------- setup kernel 1: trans_log in fp64, cast to fp32 -------------
__global__ void k_trans(float* __restrict__ ws) {
    int i = blockIdx.x;          // row (from-tempo), 0..81
    int j = threadIdx.x;         // 0..127
    __shared__ double sh[128];
    double raw = 0.0, e = 0.0;
    double ti = 28.0 + (double)i;
    if (j < NTAU) {
        double tj = 28.0 + (double)j;
        raw = -100.0 * fabs(tj / ti - 1.0);   // rowmax = raw[i][i] = 0 exactly
        e = exp(raw);
    }
    sh[j] = e;
    __syncthreads();
    for (int st = 64; st > 0; st >>= 1) {
        if (j < st) sh[j] += sh[j + st];
        __syncthreads();
    }
    double lse = log(sh[0]);
    if (j < NTAU) ws[TRANS_OFF + i * NTAU + j] = (float)(raw - lse);
}

// ---------------- setup kernel 2: emissions + zero output ---------------------
__global__ void k_emis(const float* __restrict__ logit, float* __restrict__ ws,
                       float* __restrict__ out) {
    int idx = blockIdx.x * blockDim.x + threadIdx.x;
    if (idx < BATCH * TF) {
        float x = logit[idx];
        ws[BLP_OFF + idx]  = logsig(x);
        ws[NBLP_OFF + idx] = logsig(-x);
        out[idx] = 0.0f;
    }
}

// ---------------- main kernel: chunked Viterbi + backtrace --------------------
__global__ __launch_bounds__(NTHREADS, 1)
void k_viterbi(const float* __restrict__ logit, float* __restrict__ ws,
               float* __restrict__ out) {
    const int tid = threadIdx.x;
    const int b = blockIdx.x;

    const float* transg = ws + TRANS_OFF;
    const float* blp  = ws + BLP_OFF  + b * TF;
    const float* nblp = ws + NBLP_OFF + b * TF;
    float* Ah = ws + AH_OFF + (size_t)b * TF * AP;

    __shared__ float A_lds[WMAX * AP];        // 9.4 KB: prev-last snapshots per chunk
    __shared__ float parts[4][AP * WMAX];     // 37.6 KB: max-plus partials / fb
    __shared__ float nb_w[WMAX];
    __shared__ float b_w[WMAX];
    __shared__ float rval[NTHREADS];          // final-argmax reduction
    __shared__ int   ridx[NTHREADS];

    // ---- ph2 thread mapping: (jb, iseg, tg); 28*4*9 = 1008 active ----
    const int tg   = tid % 9;
    const int iseg = (tid / 9) % 4;
    const int jb   = tid / 36;
    const bool p2act = (jb < 28);
    const int i0 = iseg * 21;
    const int j0 = jb * 3;

    // trans columns in registers: tr[k][jj] = trans[i0+k][j0+jj]
    float tr[63];
#pragma unroll
    for (int k = 0; k < 21; ++k) {
#pragma unroll
        for (int jj = 0; jj < 3; ++jj) {
            int ii = i0 + k, jx = j0 + jj;
            tr[k * 3 + jj] = (p2act && ii < NTAU && jx < NTAU)
                                 ? transg[ii * NTAU + jx] : -1.0e30f;
        }
    }

    // ---- slot init: each thread owns 6 ring slots (value in VGPR) ----
    const float logS = (float)log((double)S_TOT);
    const float b0 = blp[0], n0 = nblp[0];
    int bi6[NSLOT], tau6[NSLOT], off6[NSLOT];
    float v6[NSLOT];
#pragma unroll
    for (int k = 0; k < NSLOT; ++k) {
        int g = tid * NSLOT + k;
        if (g < S_TOT) {
            int lo = 0, hi = NTAU - 1;
            while (lo < hi) { int mid = (lo + hi + 1) >> 1;
                              if (first_of(mid) <= g) lo = mid; else hi = mid - 1; }
            int rr = g - first_of(lo);
            int ta = TMIN + lo;
            bi6[k] = lo; tau6[k] = ta;
            v6[k] = ((rr == 0) ? b0 : n0) - logS;          // delta0
            off6[k] = (rr == 0) ? (ta - 1) : (rr - 1);     // (r - 1) mod tau
        } else {
            bi6[k] = NTAU;      // pad column 82: emits land harmlessly there
            tau6[k] = 109; off6[k] = 100; v6[k] = -1.0e30f;
        }
    }

    // init A pad region so first-chunk pad-col reads are finite (never NaN)
    for (int idx = tid; idx < WMAX * AP; idx += NTHREADS) A_lds[idx] = -1.0e30f;
    __syncthreads();

    int t0 = 1;
    for (int c = 0; c < 215; ++c) {
        const int Wc = min(WMAX, TF - t0);

        if (tid < WMAX) {
            int gt = t0 + tid;
            nb_w[tid] = (tid < Wc) ? nblp[gt] : 0.0f;   // 0-pad: v += 0.0 is a no-op
            b_w[tid]  = (tid < Wc) ? blp[gt]  : 0.0f;
        }
        __syncthreads();   // B0

        float nbr[WMAX];
#pragma unroll
        for (int tt = 0; tt < WMAX; ++tt) nbr[tt] = nb_w[tt];

        // ---- ph1: register accumulate + predicated snapshot (exact op order) --
#pragma unroll
        for (int tt = 0; tt < WMAX; ++tt) {
            float nbv = nbr[tt];
#pragma unroll
            for (int k = 0; k < NSLOT; ++k) {
                if (off6[k] == tt) A_lds[tt * AP + bi6[k]] = v6[k];  // pre-add value
                v6[k] += nbv;
            }
        }
        __syncthreads();   // B1: A ready

        // A history to global (backtrace recomputes argmax from it)
        {
            float* dst = Ah + (size_t)t0 * AP;
            int n = Wc * AP;
            for (int idx = tid; idx < n; idx += NTHREADS) dst[idx] = A_lds[idx];
        }

        // ---- ph2a: max-plus partials, trans in regs ----
        if (p2act) {
            for (int tl = tg; tl < Wc; tl += 9) {
                float m0 = -INFINITY, m1 = -INFINITY, m2 = -INFINITY;
                const float* arow = &A_lds[tl * AP + i0];
#pragma unroll
                for (int k = 0; k < 21; ++k) {
                    float a = arow[k];
                    m0 = fmaxf(m0, a + tr[k * 3 + 0]);
                    m1 = fmaxf(m1, a + tr[k * 3 + 1]);
                    m2 = fmaxf(m2, a + tr[k * 3 + 2]);
                }
                parts[iseg][(j0 + 0) * WMAX + tl] = m0;
                parts[iseg][(j0 + 1) * WMAX + tl] = m1;
                parts[iseg][(j0 + 2) * WMAX + tl] = m2;
            }
        }
        __syncthreads();   // B2

        // ---- ph2b: combine 4 partials -> from_beat into parts[0] ----
        for (int cell = tid; cell < NTAU * WMAX; cell += NTHREADS) {
            int j = cell / WMAX, tl = cell % WMAX;
            if (tl < Wc) {
                int a = j * WMAX + tl;
                float v = fmaxf(fmaxf(parts[0][a], parts[1][a]),
                                fmaxf(parts[2][a], parts[3][a]));
                parts[0][a] = v;
            }
        }
        __syncthreads();   // B3

        // ---- ph3: re-seed read slots (entry + remaining nb adds, exact order) --
#pragma unroll
        for (int k = 0; k < NSLOT; ++k) {
            int off = off6[k];
            if (off < Wc) {
                float v = parts[0][bi6[k] * WMAX + off] + b_w[off];
                for (int tt = off + 1; tt < Wc; ++tt) v += nb_w[tt];
                v6[k] = v;
            }
            off -= Wc;
            if (off < 0) off += tau6[k];
            off6[k] = off;
        }
        t0 += WMAX;
        __syncthreads();   // B4: protect windows/parts before next chunk
    }

    // ---- final argmax over all states (first-max = smallest state on ties) ----
    float bv = -INFINITY; int bs = 0x7fffffff;
#pragma unroll
    for (int k = 0; k < NSLOT; ++k) {
        if (bi6[k] < NTAU) {
            int p = tau6[k] - 1 - off6[k];      // off = (r - 6000) mod tau
            int s = first_of(bi6[k]) + p;
            float v = v6[k];
            if (v > bv || (v == bv && s < bs)) { bv = v; bs = s; }
        }
    }
    rval[tid] = bv; ridx[tid] = bs;
    __syncthreads();
    for (int st = NTHREADS / 2; st > 0; st >>= 1) {
        if (tid < st) {
            float ov = rval[tid + st]; int os = ridx[tid + st];
            if (ov > rval[tid] || (ov == rval[tid] && os < ridx[tid])) {
                rval[tid] = ov; ridx[tid] = os;
            }
        }
        __syncthreads();
    }

    __threadfence();   // A-history writes visible before backtrace reads

    // ---- backtrace: wave 0, wave-parallel 82-wide argmax per beat boundary ----
    if (tid < 64) {
        const int lane = tid;
        int s = ridx[0];
        int t = TF - 1;
        for (int guard = 0; guard < 400; ++guard) {
            int lo = 0, hi = NTAU - 1;
            while (lo < hi) { int mid = (lo + hi + 1) >> 1;
                              if (first_of(mid) <= s) lo = mid; else hi = mid - 1; }
            int j = lo;
            int p = s - first_of(j);
            int tb = t - p;
            if (tb < 0) break;                 // path[0] mid-block: no beat at 0
            if (lane == 0) {
                float x = logit[b * TF + tb];
                float act = 1.0f / (1.0f + expf(-x));
                if (act >= 0.05f) out[b * TF + tb] = 1.0f;
            }
            if (tb == 0) break;
            // recompute bp argmax exactly: ascending i, strict > (first-max)
            const float* arow = Ah + (size_t)tb * AP;
            float cv = arow[lane] + transg[lane * NTAU + j];
            int ci = lane;
            if (lane < NTAU - 64) {
                float c2 = arow[64 + lane] + transg[(64 + lane) * NTAU + j];
                if (c2 > cv) { cv = c2; ci = 64 + lane; }
            }
#pragma unroll
            for (int d = 1; d < 64; d <<= 1) {
                float ov = __shfl_xor(cv, d, 64);
                int   oi = __shfl_xor(ci, d, 64);
                if (ov > cv || (ov == cv && oi < ci)) { cv = ov; ci = oi; }
            }
            s = first_of(ci) + (TMIN + ci) - 1;   // last_idx[i*]
            t = tb - 1;
        }
    }
}

extern "C" void kernel_launch(void* const* d_in, const int* in_sizes, int n_in,
                              void* d_out, int out_size, void* d_ws, size_t ws_size,
                              hipStream_t stream) {
    const float* logit = (const float*)d_in[0];
    float* out = (float*)d_out;
    float* ws = (float*)d_ws;
    k_trans<<<dim3(NTAU), dim3(128), 0, stream>>>(ws);
    k_emis<<<dim3((BATCH * TF + 255) / 256), dim3(256), 0, stream>>>(logit, ws, out);
    k_viterbi<<<dim3(BATCH), dim3(NTHREADS), 0, stream>>>(logit, ws, out);
}

// Round 2
// 2328.365 us; speedup vs baseline: 1.7464x; 1.7464x over previous
//
#include <hip/hip_runtime.h>
#include <math.h>

#define NTAU 82
#define TMIN 28
#define S_TOT 5617
#define TF 6000
#define BATCH 4
#define WMAX 28
#define AP 84            // A row pitch (82 + 2 pad); 84*4B = 336B = 21*16 -> rows 16B-aligned
#define NSLOT 6
#define NTHREADS 1024
#define NCHUNK 215
#define CHUNK_F (WMAX * AP)   // 2352 floats per chunk of A-history

// ws layout (float offsets)
#define TRANS_OFF 0            // 82*82
#define BLP_OFF   8192         // 4*6000
#define NBLP_OFF  32768        // 4*6000
#define AH_OFF    57344        // 4 * 215 * 2352  (chunk-major A history)
// total = 57344 + 2,022,720 floats = 8.32 MB

__device__ __forceinline__ int first_of(int b) { return b * (55 + b) / 2; }

__device__ __forceinline__ float logsig(float x) {
    return -(fmaxf(-x, 0.0f) + log1pf(expf(-fabsf(x))));
}

// ---------------- setup kernel 1: trans_log in fp64, cast to fp32 -------------
__global__ void k_trans(float* __restrict__ ws) {
    int i = blockIdx.x;
    int j = threadIdx.x;
    __shared__ double sh[128];
    double raw = 0.0, e = 0.0;
    double ti = 28.0 + (double)i;
    if (j < NTAU) {
        double tj = 28.0 + (double)j;
        raw = -100.0 * fabs(tj / ti - 1.0);
        e = exp(raw);
    }
    sh[j] = e;
    __syncthreads();
    for (int st = 64; st > 0; st >>= 1) {
        if (j < st) sh[j] += sh[j + st];
        __syncthreads();
    }
    double lse = log(sh[0]);
    if (j < NTAU) ws[TRANS_OFF + i * NTAU + j] = (float)(raw - lse);
}

// ---------------- setup kernel 2: emissions + zero output ---------------------
__global__ void k_emis(const float* __restrict__ logit, float* __restrict__ ws,
                       float* __restrict__ out) {
    int idx = blockIdx.x * blockDim.x + threadIdx.x;
    if (idx < BATCH * TF) {
        float x = logit[idx];
        ws[BLP_OFF + idx]  = logsig(x);
        ws[NBLP_OFF + idx] = logsig(-x);
        out[idx] = 0.0f;
    }
}

// ---------------- main kernel: chunked Viterbi + backtrace --------------------
__global__ __launch_bounds__(NTHREADS, 4)
void k_viterbi(const float* __restrict__ logit, float* __restrict__ ws,
               float* __restrict__ out) {
    const int tid = threadIdx.x;
    const int b = blockIdx.x;

    const float* transg = ws + TRANS_OFF;
    const float* blp  = ws + BLP_OFF  + b * TF;
    const float* nblp = ws + NBLP_OFF + b * TF;
    float* Ah = ws + AH_OFF + (size_t)b * (NCHUNK * CHUNK_F);

    __shared__ float A_lds[(WMAX + 1) * AP];   // rows 0..27 real, row 28 = dump
    __shared__ float parts[4][AP * WMAX];      // partials: [iseg][j*28 + tl]
    __shared__ float win_nb[4][WMAX];          // quad-buffered emission windows
    __shared__ float win_b[4][WMAX];
    __shared__ float rval[NTHREADS];
    __shared__ int   ridx[NTHREADS];

    // ---- ph2 mapping: tg = tl-group (6), jb = j-pair (42), iseg = i-segment (4) --
    const int tg   = tid % 6;
    const int jb   = (tid / 6) % 42;
    const int iseg = tid / 252;          // 0..3 active, 4 = idle (tid>=1008)
    const bool p2act = (tid < 1008);
    const int i0 = iseg * 20;            // segments 20/20/20/22; byte offs 0/80/160/240 (16B-aligned)
    const int j0 = jb * 2;               // j0, j0+1 (82,83 = pad)

    // trans columns in registers: tr0/tr1[k] = trans[i0+k][j0 / j0+1]
    float tr0[22], tr1[22];
    if (p2act) {
#pragma unroll
        for (int k = 0; k < 22; ++k) {
            int ii = i0 + k;
            bool vi = (k < 20) || (iseg == 3);
            tr0[k] = (vi && ii < NTAU && (j0 + 0) < NTAU) ? transg[ii * NTAU + j0]     : -1.0e30f;
            tr1[k] = (vi && ii < NTAU && (j0 + 1) < NTAU) ? transg[ii * NTAU + j0 + 1] : -1.0e30f;
        }
    }

    // ---- slot init ----
    const float logS = (float)log((double)S_TOT);
    const float b0 = blp[0], n0 = nblp[0];
    int bi6[NSLOT], off6[NSLOT];
    float v6[NSLOT], snap6[NSLOT], vA[NSLOT];
#pragma unroll
    for (int k = 0; k < NSLOT; ++k) {
        int g = tid * NSLOT + k;
        snap6[k] = -1.0e30f;
        vA[k] = -1.0e30f;
        if (g < S_TOT) {
            int lo = 0, hi = NTAU - 1;
            while (lo < hi) { int mid = (lo + hi + 1) >> 1;
                              if (first_of(mid) <= g) lo = mid; else hi = mid - 1; }
            int rr = g - first_of(lo);
            int ta = TMIN + lo;
            bi6[k] = lo;
            v6[k] = ((rr == 0) ? b0 : n0) - logS;
            off6[k] = (rr == 0) ? (ta - 1) : (rr - 1);
        } else {
            bi6[k] = NTAU; off6[k] = 100; v6[k] = -1.0e30f;
        }
    }

    // window loader: chunk cc covers t = 1+28cc .. 1+28cc+27 (zero-padded past 5999)
    auto winload = [&](int cc) {
        if (cc < NCHUNK && tid < WMAX) {
            int gt = 1 + cc * WMAX + tid;
            win_nb[cc & 3][tid] = (gt < TF) ? nblp[gt] : 0.0f;
            win_b [cc & 3][tid] = (gt < TF) ? blp[gt]  : 0.0f;
        }
    };
    winload(0);
    winload(1);
    __syncthreads();

    for (int c = 0; c < NCHUNK; ++c) {
        const int buf = c & 3;

        // ---- window to registers (b128 loads, then fully-unrolled reg array) ----
        float nbr[WMAX];
        {
            const float4* wn4 = (const float4*)&win_nb[buf][0];
#pragma unroll
            for (int q = 0; q < 7; ++q) {
                float4 t4 = wn4[q];
                nbr[4*q+0] = t4.x; nbr[4*q+1] = t4.y; nbr[4*q+2] = t4.z; nbr[4*q+3] = t4.w;
            }
        }

        // ---- ph1: select-capture snapshot + unconditional adds (3 VALU / slot-step) --
#pragma unroll
        for (int tt = 0; tt < WMAX; ++tt) {
            const float nbv = nbr[tt];
#pragma unroll
            for (int k = 0; k < NSLOT; ++k) {
                snap6[k] = (off6[k] == tt) ? v6[k] : snap6[k];
                v6[k] += nbv;
            }
        }
        // 6 unpredicated LDS writes (dump row for non-snapshot slots)
#pragma unroll
        for (int k = 0; k < NSLOT; ++k) {
            int row = (off6[k] < WMAX) ? off6[k] : WMAX;
            A_lds[row * AP + bi6[k]] = snap6[k];
        }

        winload(c + 2);   // safe: buffer (c+2)&3 last read before B1(c-1)

        if (c == NCHUNK - 1) {        // save post-ph1 values for final argmax
#pragma unroll
            for (int k = 0; k < NSLOT; ++k) vA[k] = v6[k];
        }
        __syncthreads();   // B1: A snapshots ready

        // ---- A history to global (coalesced float4) ----
        if (tid < CHUNK_F / 4) {
            float4 v4 = *(const float4*)&A_lds[tid * 4];
            *(float4*)&Ah[(size_t)c * CHUNK_F + tid * 4] = v4;
        }

        // ---- ph2a: max-plus partials, trans in regs, A rows via b128 ----
        if (p2act) {
#pragma unroll
            for (int u = 0; u < 5; ++u) {
                const int tl = tg + 6 * u;
                if (tl < WMAX) {
                    const float4* ar4 = (const float4*)&A_lds[tl * AP + i0];
                    float m0 = -INFINITY, m1 = -INFINITY;
#pragma unroll
                    for (int q = 0; q < 5; ++q) {
                        float4 a = ar4[q];
                        m0 = fmaxf(m0, a.x + tr0[4*q+0]); m1 = fmaxf(m1, a.x + tr1[4*q+0]);
                        m0 = fmaxf(m0, a.y + tr0[4*q+1]); m1 = fmaxf(m1, a.y + tr1[4*q+1]);
                        m0 = fmaxf(m0, a.z + tr0[4*q+2]); m1 = fmaxf(m1, a.z + tr1[4*q+2]);
                        m0 = fmaxf(m0, a.w + tr0[4*q+3]); m1 = fmaxf(m1, a.w + tr1[4*q+3]);
                    }
                    if (iseg == 3) {
                        float a20 = A_lds[tl * AP + 80];
                        float a21 = A_lds[tl * AP + 81];
                        m0 = fmaxf(m0, a20 + tr0[20]); m1 = fmaxf(m1, a20 + tr1[20]);
                        m0 = fmaxf(m0, a21 + tr0[21]); m1 = fmaxf(m1, a21 + tr1[21]);
                    }
                    parts[iseg][(j0 + 0) * WMAX + tl] = m0;
                    parts[iseg][(j0 + 1) * WMAX + tl] = m1;
                }
            }
        }
        __syncthreads();   // B2: partials ready

        // ---- ph3: hoisted reset + fully-unrolled conditional tail adds ----
#pragma unroll
        for (int k = 0; k < NSLOT; ++k) {
            const int oc = min(off6[k], WMAX - 1);
            const int pidx = bi6[k] * WMAX + oc;
            float e = fmaxf(fmaxf(parts[0][pidx], parts[1][pidx]),
                            fmaxf(parts[2][pidx], parts[3][pidx]));
            float ventry = e + win_b[buf][oc];
            v6[k] = (off6[k] < WMAX) ? ventry : v6[k];
        }
#pragma unroll
        for (int tt = 1; tt < WMAX; ++tt) {
            const float nbv = nbr[tt];
#pragma unroll
            for (int k = 0; k < NSLOT; ++k)
                v6[k] += (tt > off6[k]) ? nbv : 0.0f;   // +0.0 exact (values < 0)
        }
#pragma unroll
        for (int k = 0; k < NSLOT; ++k) {
            off6[k] -= WMAX;
            if (off6[k] < 0) off6[k] += TMIN + bi6[k];
        }
        // no end barrier: next ph1 touches only regs + A_lds (reads done pre-B2);
        // next winload's buffer last read before B1 of previous chunk.
    }

    // ---- final argmax (chunk 214 real width = 7; recover exact t=5999 values) ----
    float bv = -INFINITY; int bs = 0x7fffffff;
#pragma unroll
    for (int k = 0; k < NSLOT; ++k) {
        if (bi6[k] < NTAU) {
            const int tau = TMIN + bi6[k];
            int offA = off6[k] + WMAX; if (offA >= tau) offA -= tau;  // undo last update
            int offT = offA - 7; if (offT < 0) offT += tau;           // true Wc=7 update
            const int p = tau - 1 - offT;
            const int s = first_of(bi6[k]) + p;
            // reset in real region (tt<=6): post-ph3 value is exact (pad adds are +0);
            // otherwise ph1-end value is exact (hoisted pad-reset corrupted v6).
            const float v = (offA <= 6) ? v6[k] : vA[k];
            if (v > bv || (v == bv && s < bs)) { bv = v; bs = s; }
        }
    }
    rval[tid] = bv; ridx[tid] = bs;
    __syncthreads();
    for (int st = NTHREADS / 2; st > 0; st >>= 1) {
        if (tid < st) {
            float ov = rval[tid + st]; int os = ridx[tid + st];
            if (ov > rval[tid] || (ov == rval[tid] && os < ridx[tid])) {
                rval[tid] = ov; ridx[tid] = os;
            }
        }
        __syncthreads();
    }

    __threadfence();   // Ah global writes visible before backtrace reads

    // ---- backtrace: wave 0, wave-parallel 82-wide argmax per beat boundary ----
    if (tid < 64) {
        const int lane = tid;
        int s = ridx[0];
        int t = TF - 1;
        for (int guard = 0; guard < 400; ++guard) {
            int lo = 0, hi = NTAU - 1;
            while (lo < hi) { int mid = (lo + hi + 1) >> 1;
                              if (first_of(mid) <= s) lo = mid; else hi = mid - 1; }
            int j = lo;
            int p = s - first_of(j);
            int tb = t - p;
            if (tb < 0) break;
            if (lane == 0) {
                float x = logit[b * TF + tb];
                float act = 1.0f / (1.0f + expf(-x));
                if (act >= 0.05f) out[b * TF + tb] = 1.0f;
            }
            if (tb == 0) break;
            const int tq = tb - 1;
            const float* arow = Ah + (size_t)(tq / WMAX) * CHUNK_F + (tq % WMAX) * AP;
            float cv = arow[lane] + transg[lane * NTAU + j];
            int ci = lane;
            if (lane < NTAU - 64) {
                float c2 = arow[64 + lane] + transg[(64 + lane) * NTAU + j];
                if (c2 > cv) { cv = c2; ci = 64 + lane; }
            }
#pragma unroll
            for (int d = 1; d < 64; d <<= 1) {
                float ov = __shfl_xor(cv, d, 64);
                int   oi = __shfl_xor(ci, d, 64);
                if (ov > cv || (ov == cv && oi < ci)) { cv = ov; ci = oi; }
            }
            s = first_of(ci) + (TMIN + ci) - 1;
            t = tb - 1;
        }
    }
}

extern "C" void kernel_launch(void* const* d_in, const int* in_sizes, int n_in,
                              void* d_out, int out_size, void* d_ws, size_t ws_size,
                              hipStream_t stream) {
    const float* logit = (const float*)d_in[0];
    float* out = (float*)d_out;
    float* ws = (float*)d_ws;
    k_trans<<<dim3(NTAU), dim3(128), 0, stream>>>(ws);
    k_emis<<<dim3((BATCH * TF + 255) / 256), dim3(256), 0, stream>>>(logit, ws, out);
    k_viterbi<<<dim3(BATCH), dim3(NTHREADS), 0, stream>>>(logit, ws, out);
}

// Round 3
// 1555.246 us; speedup vs baseline: 2.6146x; 1.4971x over previous
//
#include <hip/hip_runtime.h>
#include <math.h>

#define NTAU 82
#define TMIN 28
#define S_TOT 5617
#define TF 6000
#define BATCH 4
#define WMAX 28
#define AP 84            // A/fb row pitch: 82 + 2 pad; 84*4B = 336B (16B-aligned rows)
#define NTHREADS 1024
#define NCHUNK 215
#define CHUNK_F (WMAX * AP)   // 2352 floats per chunk of A-history

// ws layout (float offsets)
#define TRANS_OFF 0            // 82*82
#define BLP_OFF   8192         // 4*6000
#define NBLP_OFF  32768        // 4*6000
#define AH_OFF    57344        // 4 * 215 * 2352 (chunk-major A history)

__device__ __forceinline__ int first_of(int b) { return b * (55 + b) / 2; }
__device__ __forceinline__ int nf_of(int b)    { return b * (b - 1) / 2; }   // # non-reset slots before block b

__device__ __forceinline__ float logsig(float x) {
    return -(fmaxf(-x, 0.0f) + log1pf(expf(-fabsf(x))));
}

// ---------------- setup kernel 1: trans_log in fp64, cast to fp32 -------------
__global__ void k_trans(float* __restrict__ ws) {
    int i = blockIdx.x;
    int j = threadIdx.x;
    __shared__ double sh[128];
    double raw = 0.0, e = 0.0;
    double ti = 28.0 + (double)i;
    if (j < NTAU) {
        double tj = 28.0 + (double)j;
        raw = -100.0 * fabs(tj / ti - 1.0);
        e = exp(raw);
    }
    sh[j] = e;
    __syncthreads();
    for (int st = 64; st > 0; st >>= 1) {
        if (j < st) sh[j] += sh[j + st];
        __syncthreads();
    }
    double lse = log(sh[0]);
    if (j < NTAU) ws[TRANS_OFF + i * NTAU + j] = (float)(raw - lse);
}

// ---------------- setup kernel 2: emissions + zero output ---------------------
__global__ void k_emis(const float* __restrict__ logit, float* __restrict__ ws,
                       float* __restrict__ out) {
    int idx = blockIdx.x * blockDim.x + threadIdx.x;
    if (idx < BATCH * TF) {
        float x = logit[idx];
        ws[BLP_OFF + idx]  = logsig(x);
        ws[NBLP_OFF + idx] = logsig(-x);
        out[idx] = 0.0f;
    }
}

// ---------------- main kernel: chunked Viterbi + backtrace --------------------
__global__ __attribute__((amdgpu_flat_work_group_size(NTHREADS, NTHREADS),
                          amdgpu_waves_per_eu(4, 4)))
void k_viterbi(const float* __restrict__ logit, float* __restrict__ ws,
               float* __restrict__ out) {
    const int tid = threadIdx.x;
    const int b = blockIdx.x;

    const float* transg = ws + TRANS_OFF;
    const float* blp  = ws + BLP_OFF  + b * TF;
    const float* nblp = ws + NBLP_OFF + b * TF;
    float* Ah = ws + AH_OFF + (size_t)b * (NCHUNK * CHUNK_F);

    __shared__ float V[5632];                     // slot values, idx = first_of(b)+r
    __shared__ __align__(16) float A_lds[CHUNK_F];// captures (prev_last) [tt][i]
    __shared__ __align__(16) float fb[CHUNK_F];   // from_beat [tt][j]
    __shared__ __align__(16) float win_nb[4][WMAX];
    __shared__ __align__(16) float win_b[4][WMAX];
    __shared__ float wv[16];
    __shared__ int   wi[16];

    // ---- ph2 mapping: quad = (jp,tg), lanes within quad = iseg (i-quarter) ----
    const int iseg = tid & 3;
    const int jp   = (tid >> 2) % 41;     // j-pair, j0 = 2*jp (0..80)
    const int tg   = tid / 164;           // quad-uniform (164 = 4*41)
    const bool p2act = (tid < 984);       // 4*41*6
    const int i0 = iseg * 20;             // 20/20/20/22 split
    const int j0 = jp * 2;

    float tr0[22], tr1[22];
#pragma unroll
    for (int k = 0; k < 22; ++k) { tr0[k] = -1.0e30f; tr1[k] = -1.0e30f; }
    if (p2act) {
        const int icnt = (iseg == 3) ? 22 : 20;
#pragma unroll
        for (int k = 0; k < 22; ++k) {
            if (k < icnt) {
                tr0[k] = transg[(i0 + k) * NTAU + j0];
                tr1[k] = transg[(i0 + k) * NTAU + j0 + 1];
            }
        }
    }

    // ---- reset-slot mapping: thread = (off o, base-block s); blocks s,s+36,s+72 --
    const bool ract = (tid < 1008);       // 28*36
    const int ro = ract ? (tid / 36) : 27;
    const int rs = tid % 36;
    const bool rv2 = ract && (rs < 10);   // third block only if s+72 < 82
    const int rb0 = rs, rb1 = rs + 36, rb2 = rs + 72;
    const int rt0 = TMIN + rb0, rt1 = TMIN + rb1, rt2 = TMIN + (rv2 ? rb2 : 0);
    const int rf0 = first_of(rb0), rf1 = first_of(rb1), rf2 = rv2 ? first_of(rb2) : 0;
    int rr0 = ro, rr1 = ro, rr2 = ro;     // ring index r = (o + 28c) mod tau

    // ---- non-reset mapping: flat f over sum(tau-28)=3321, static 4 per thread ---
    int nrR[4], nrFo[4], nrTau[4];
    bool nrV[4];
#pragma unroll
    for (int q = 0; q < 4; ++q) {
        const int f = tid + q * NTHREADS;
        nrV[q] = (f < 3321);
        nrR[q] = 0; nrFo[q] = 0; nrTau[q] = 109;
        if (nrV[q]) {
            int lo = 1, hi = NTAU - 1;    // largest b with nf_of(b) <= f
            while (lo < hi) { int mid = (lo + hi + 1) >> 1;
                              if (nf_of(mid) <= f) lo = mid; else hi = mid - 1; }
            const int m = f - nf_of(lo);
            nrR[q]   = TMIN + m;          // r at chunk 0 = 28 + m
            nrFo[q]  = first_of(lo);
            nrTau[q] = TMIN + lo;
        }
    }

    // ---- V init: slot (b,r) holds delta0 of position rr=(r+1)%tau --------------
    const float logS = (float)log((double)S_TOT);
    const float b0 = blp[0], n0 = nblp[0];
    for (int g = tid; g < S_TOT; g += NTHREADS) {
        int lo = 0, hi = NTAU - 1;
        while (lo < hi) { int mid = (lo + hi + 1) >> 1;
                          if (first_of(mid) <= g) lo = mid; else hi = mid - 1; }
        const int tau = TMIN + lo;
        const int r = g - first_of(lo);
        V[g] = ((r == tau - 1) ? b0 : n0) - logS;
    }

    auto winload = [&](int cc) {
        if (cc < NCHUNK && tid < WMAX) {
            int gt = 1 + cc * WMAX + tid;
            win_nb[cc & 3][tid] = (gt < TF) ? nblp[gt] : 0.0f;
            win_b [cc & 3][tid] = (gt < TF) ? blp[gt]  : 0.0f;
        }
    };
    winload(0);
    winload(1);
    __syncthreads();

    float cv0 = 0.0f, cv1 = 0.0f, cv2 = 0.0f;
    for (int c = 0; c < NCHUNK; ++c) {
        const int buf = c & 3;

        // window to registers (for non-reset unrolled adds)
        float nbr[WMAX];
        {
            const float4* wn4 = (const float4*)&win_nb[buf][0];
#pragma unroll
            for (int qq = 0; qq < 7; ++qq) {
                float4 t4 = wn4[qq];
                nbr[4*qq+0] = t4.x; nbr[4*qq+1] = t4.y; nbr[4*qq+2] = t4.z; nbr[4*qq+3] = t4.w;
            }
        }

        // ---- prefix: capture value C = V + nb[0..o-1] (exact sequential) ----
        cv0 = ract ? V[rf0 + rr0] : 0.0f;
        cv1 = ract ? V[rf1 + rr1] : 0.0f;
        cv2 = rv2  ? V[rf2 + rr2] : 0.0f;
        for (int tt = 0; tt < ro; ++tt) {
            const float w = win_nb[buf][tt];
            cv0 += w; cv1 += w; cv2 += w;
        }
        if (ract) {
            A_lds[ro * AP + rb0] = cv0;
            A_lds[ro * AP + rb1] = cv1;
            if (rv2) A_lds[ro * AP + rb2] = cv2;
        }
        winload(c + 2);
        __syncthreads();   // B1: captures ready

        // ---- A history to global (coalesced float4) ----
        if (tid < CHUNK_F / 4) {
            float4 v4 = ((const float4*)A_lds)[tid];
            ((float4*)(Ah + (size_t)c * CHUNK_F))[tid] = v4;
        }

        // ---- ph2: from_beat via max-plus, 4-lane shuffle reduce ----
        if (p2act) {
#pragma unroll
            for (int u = 0; u < 5; ++u) {
                const int tl = tg + 6 * u;
                if (tl < WMAX) {
                    const float4* ar4 = (const float4*)&A_lds[tl * AP + i0];
                    float m0 = -INFINITY, m1 = -INFINITY;
#pragma unroll
                    for (int q = 0; q < 5; ++q) {
                        float4 a = ar4[q];
                        m0 = fmaxf(m0, a.x + tr0[4*q+0]); m1 = fmaxf(m1, a.x + tr1[4*q+0]);
                        m0 = fmaxf(m0, a.y + tr0[4*q+1]); m1 = fmaxf(m1, a.y + tr1[4*q+1]);
                        m0 = fmaxf(m0, a.z + tr0[4*q+2]); m1 = fmaxf(m1, a.z + tr1[4*q+2]);
                        m0 = fmaxf(m0, a.w + tr0[4*q+3]); m1 = fmaxf(m1, a.w + tr1[4*q+3]);
                    }
                    if (iseg == 3) {
                        float a20 = A_lds[tl * AP + 80];
                        float a21 = A_lds[tl * AP + 81];
                        m0 = fmaxf(m0, a20 + tr0[20]); m1 = fmaxf(m1, a20 + tr1[20]);
                        m0 = fmaxf(m0, a21 + tr0[21]); m1 = fmaxf(m1, a21 + tr1[21]);
                    }
                    m0 = fmaxf(m0, __shfl_xor(m0, 1)); m1 = fmaxf(m1, __shfl_xor(m1, 1));
                    m0 = fmaxf(m0, __shfl_xor(m0, 2)); m1 = fmaxf(m1, __shfl_xor(m1, 2));
                    if (iseg == 0) *(float2*)&fb[tl * AP + j0] = make_float2(m0, m1);
                }
            }
        }

        // ---- non-reset slots: 28 unpredicated sequential adds ----
#pragma unroll
        for (int q = 0; q < 4; ++q) {
            if (nrV[q]) {
                const int a = nrFo[q] + nrR[q];
                float v = V[a];
#pragma unroll
                for (int tt = 0; tt < WMAX; ++tt) v += nbr[tt];
                V[a] = v;
            }
        }
        __syncthreads();   // B2: fb ready

        // ---- entry + suffix for reset slots (exact sequential) ----
        {
            const float bw = win_b[buf][ro];
            float e0 = ract ? (fb[ro * AP + rb0] + bw) : 0.0f;
            float e1 = ract ? (fb[ro * AP + rb1] + bw) : 0.0f;
            float e2 = rv2  ? (fb[ro * AP + rb2] + bw) : 0.0f;
            for (int tt = ro + 1; tt < WMAX; ++tt) {
                const float w = win_nb[buf][tt];
                e0 += w; e1 += w; e2 += w;
            }
            // last chunk: resets at padded times (o>=7) must not happen;
            // capture C == final value there (pad adds are +0.0, exact)
            const bool keepC = (c == NCHUNK - 1) && (ro >= 7);
            if (ract) {
                V[rf0 + rr0] = keepC ? cv0 : e0;
                V[rf1 + rr1] = keepC ? cv1 : e1;
                if (rv2) V[rf2 + rr2] = keepC ? cv2 : e2;
            }
            rr0 += WMAX; if (rr0 >= rt0) rr0 -= rt0;
            rr1 += WMAX; if (rr1 >= rt1) rr1 -= rt1;
            rr2 += WMAX; if (rr2 >= rt2) rr2 -= rt2;
        }
#pragma unroll
        for (int q = 0; q < 4; ++q) {
            if (nrV[q]) { nrR[q] += WMAX; if (nrR[q] >= nrTau[q]) nrR[q] -= nrTau[q]; }
        }
        __syncthreads();   // B3: protect V writes from next chunk's prefix reads
    }

    // ---- final argmax over V (state s from ring index: p = (5998 - r) mod tau) --
    float bvv = -INFINITY; int bss = 0x7fffffff;
    for (int g = tid; g < S_TOT; g += NTHREADS) {
        int lo = 0, hi = NTAU - 1;
        while (lo < hi) { int mid = (lo + hi + 1) >> 1;
                          if (first_of(mid) <= g) lo = mid; else hi = mid - 1; }
        const int tau = TMIN + lo;
        const int r = g - first_of(lo);
        const int p = (5998 - r) % tau;
        const int s = first_of(lo) + p;
        const float v = V[g];
        if (v > bvv || (v == bvv && s < bss)) { bvv = v; bss = s; }
    }
#pragma unroll
    for (int d = 1; d < 64; d <<= 1) {
        float ov = __shfl_xor(bvv, d);
        int   os = __shfl_xor(bss, d);
        if (ov > bvv || (ov == bvv && os < bss)) { bvv = ov; bss = os; }
    }
    if ((tid & 63) == 0) { wv[tid >> 6] = bvv; wi[tid >> 6] = bss; }
    __syncthreads();

    __threadfence();   // Ah global writes visible before backtrace reads

    // ---- backtrace: wave 0, wave-parallel 82-wide argmax per beat boundary ----
    if (tid < 64) {
        const int lane = tid;
        float bvF = (lane < 16) ? wv[lane] : -INFINITY;
        int   bvI = (lane < 16) ? wi[lane] : 0x7fffffff;
#pragma unroll
        for (int d = 1; d < 16; d <<= 1) {
            float ov = __shfl_xor(bvF, d);
            int   os = __shfl_xor(bvI, d);
            if (ov > bvF || (ov == bvF && os < bvI)) { bvF = ov; bvI = os; }
        }
        int s = __shfl(bvI, 0);
        int t = TF - 1;
        for (int guard = 0; guard < 400; ++guard) {
            int lo = 0, hi = NTAU - 1;
            while (lo < hi) { int mid = (lo + hi + 1) >> 1;
                              if (first_of(mid) <= s) lo = mid; else hi = mid - 1; }
            int j = lo;
            int p = s - first_of(j);
            int tb = t - p;
            if (tb < 0) break;
            if (lane == 0) {
                float x = logit[b * TF + tb];
                float act = 1.0f / (1.0f + expf(-x));
                if (act >= 0.05f) out[b * TF + tb] = 1.0f;
            }
            if (tb == 0) break;
            const int tq = tb - 1;
            const float* arow = Ah + (size_t)(tq / WMAX) * CHUNK_F + (tq % WMAX) * AP;
            float cvv = arow[lane] + transg[lane * NTAU + j];
            int ci = lane;
            if (lane < NTAU - 64) {
                float c2 = arow[64 + lane] + transg[(64 + lane) * NTAU + j];
                if (c2 > cvv) { cvv = c2; ci = 64 + lane; }
            }
#pragma unroll
            for (int d = 1; d < 64; d <<= 1) {
                float ov = __shfl_xor(cvv, d, 64);
                int   oi = __shfl_xor(ci, d, 64);
                if (ov > cvv || (ov == cvv && oi < ci)) { cvv = ov; ci = oi; }
            }
            s = first_of(ci) + (TMIN + ci) - 1;   // last_idx[i*]
            t = tb - 1;
        }
    }
}

extern "C" void kernel_launch(void* const* d_in, const int* in_sizes, int n_in,
                              void* d_out, int out_size, void* d_ws, size_t ws_size,
                              hipStream_t stream) {
    const float* logit = (const float*)d_in[0];
    float* out = (float*)d_out;
    float* ws = (float*)d_ws;
    k_trans<<<dim3(NTAU), dim3(128), 0, stream>>>(ws);
    k_emis<<<dim3((BATCH * TF + 255) / 256), dim3(256), 0, stream>>>(logit, ws, out);
    k_viterbi<<<dim3(BATCH), dim3(NTHREADS), 0, stream>>>(logit, ws, out);
}